// Round 7
// baseline (223.430 us; speedup 1.0000x reference)
//
#include <hip/hip_runtime.h>

#define N_NODES 2000
#define NP      2048    // Sp n-dim padding
#define KB      63      // real k-blocks (k = 2000 padded to 2016 in-block)
#define KB2     64      // loop k-blocks (kb=63 slab of Sp zero-filled)
#define BATCH   32
#define DIM     64      // DIM_IN == DIM_OUT
#define EMB     16
#define KI      192     // CHEB_K * DIM_IN
#define WCOLS   12288   // DIM_OUT * KI

typedef __bf16 bf16;
typedef __attribute__((ext_vector_type(8))) __bf16 bf16x8;
typedef __attribute__((ext_vector_type(4))) float  f32x4;

struct alignas(8) bf16x4pk { bf16 v[4]; };

// ---------------------------------------------------------------------------
// Kernel 1: softmax(relu(nv1@nv2)) row -> Sp packed [kb][n(pad 2048)][kk]
// ---------------------------------------------------------------------------
__global__ __launch_bounds__(256) void adj_softmax_pack(
    const float* __restrict__ nv1, const float* __restrict__ nv2,
    bf16* __restrict__ Sp)
{
    const int row = blockIdx.x;
    const int tid = threadIdx.x;
    const int j0  = tid * 8;
    __shared__ float sa[EMB];
    __shared__ float wred[4];
    __shared__ float bcast;
    if (tid < EMB) sa[tid] = nv1[row * EMB + tid];
    __syncthreads();

    const bool active = (tid < 250);
    float v[8] = {0,0,0,0,0,0,0,0};
    if (active) {
#pragma unroll
        for (int d = 0; d < EMB; ++d) {
            const float sd = sa[d];
            const float4 q0 = *(const float4*)&nv2[d * N_NODES + j0];
            const float4 q1 = *(const float4*)&nv2[d * N_NODES + j0 + 4];
            v[0] += sd * q0.x; v[1] += sd * q0.y; v[2] += sd * q0.z; v[3] += sd * q0.w;
            v[4] += sd * q1.x; v[5] += sd * q1.y; v[6] += sd * q1.z; v[7] += sd * q1.w;
        }
    }
    float lmax = 0.0f;
#pragma unroll
    for (int jj = 0; jj < 8; ++jj) { v[jj] = fmaxf(v[jj], 0.0f); lmax = fmaxf(lmax, v[jj]); }
#pragma unroll
    for (int off = 32; off > 0; off >>= 1)
        lmax = fmaxf(lmax, __shfl_down(lmax, off, 64));
    if ((tid & 63) == 0) wred[tid >> 6] = lmax;
    __syncthreads();
    if (tid == 0) bcast = fmaxf(fmaxf(wred[0], wred[1]), fmaxf(wred[2], wred[3]));
    __syncthreads();
    const float rmax = bcast;

    float lsum = 0.0f;
    if (active) {
#pragma unroll
        for (int jj = 0; jj < 8; ++jj) { v[jj] = __expf(v[jj] - rmax); lsum += v[jj]; }
    }
#pragma unroll
    for (int off = 32; off > 0; off >>= 1)
        lsum += __shfl_down(lsum, off, 64);
    if ((tid & 63) == 0) wred[tid >> 6] = lsum;
    __syncthreads();
    if (tid == 0) bcast = wred[0] + wred[1] + wred[2] + wred[3];
    __syncthreads();
    const float inv = 1.0f / bcast;

    if (tid < 252) {
        bf16x8 pk;
#pragma unroll
        for (int jj = 0; jj < 8; ++jj)
            pk[jj] = (bf16)(active ? v[jj] * inv : 0.0f);
        const int kb = j0 >> 5, kk = j0 & 31;
        *(bf16x8*)&Sp[((size_t)kb * NP + row) * 32 + kk] = pk;
    }
}

// ---------------------------------------------------------------------------
// Kernel 2: x [b][m][c] fp32 -> xTp packed [b][kb][c][kk] bf16 + xbf row-major
// ---------------------------------------------------------------------------
__global__ __launch_bounds__(256) void transpose_pack_x(
    const float* __restrict__ X, bf16* __restrict__ Xtp, bf16* __restrict__ Xbf)
{
    const int b  = blockIdx.y;
    const int m0 = blockIdx.x * 64;
    const int tid = threadIdx.x;
    __shared__ bf16 T[64][72];
#pragma unroll
    for (int i = 0; i < 4; ++i) {
        int idx = i * 256 + tid;
        int r  = idx >> 4;
        int c4 = (idx & 15) * 4;
        int m  = m0 + r;
        float4 v = make_float4(0.f, 0.f, 0.f, 0.f);
        if (m < N_NODES)
            v = *(const float4*)&X[((size_t)b * N_NODES + m) * DIM + c4];
        bf16x4pk pk;
        pk.v[0] = (bf16)v.x; pk.v[1] = (bf16)v.y;
        pk.v[2] = (bf16)v.z; pk.v[3] = (bf16)v.w;
        if (m < N_NODES)
            *(bf16x4pk*)&Xbf[((size_t)b * N_NODES + m) * DIM + c4] = pk;
        T[c4 + 0][r] = pk.v[0];
        T[c4 + 1][r] = pk.v[1];
        T[c4 + 2][r] = pk.v[2];
        T[c4 + 3][r] = pk.v[3];
    }
    __syncthreads();
#pragma unroll
    for (int i = 0; i < 2; ++i) {
        int idx = i * 256 + tid;
        int c   = idx >> 3;
        int mch = idx & 7;
        int kb  = (m0 >> 5) + (mch >> 2);
        if (kb < KB) {
            int kk = (mch & 3) * 8;
            bf16x8 vv = *(const bf16x8*)&T[c][mch * 8];
            *(bf16x8*)&Xtp[((size_t)(b * KB2 + kb) * DIM + c) * 32 + kk] = vv;
        }
    }
}

// ---------------------------------------------------------------------------
// Kernel 3: LDS-free fragment-direct MFMA spmm, 4-deep rotating register
// pipeline over KB2=64 k-blocks. __launch_bounds__(256,2) unlocks a 256-VGPR
// budget so the 4 stages (96 VGPR bufs) stay live (R6: default budget 64 VGPR
// collapsed the pipeline -> 990 cyc/stage serialization).
// Grid x = n-tile (fastest) -> each XCD sees ~2 A-tiles (1 MB, L2-resident).
// ---------------------------------------------------------------------------
__global__ __launch_bounds__(256, 2) void spmm_pack(
    const bf16* __restrict__ Ap, const bf16* __restrict__ Btp,
    bf16* __restrict__ Ybf, bf16* __restrict__ Ytp, int write_ytp)
{
    const int nt  = blockIdx.x;
    const int b   = blockIdx.y;
    const int n0  = nt * 128;
    const int tid = threadIdx.x;
    const int lane = tid & 63, wave = tid >> 6;
    const int wm = wave >> 1, wn = wave & 1;
    const int l15 = lane & 15, quad = lane >> 4;

    const bf16* ab = Ap + ((size_t)(n0 + wm * 64 + l15)) * 32 + quad * 8;
    const bf16* bb = Btp + ((size_t)(b * KB2) * DIM + wn * 32 + l15) * 32 + quad * 8;

    f32x4 acc[4][2] = {};
    bf16x8 abuf[4][4], bbuf[4][2];

#define LOAD_ST(st, kb_) {                                               \
        const bf16* pa = ab + (size_t)(kb_) * (NP * 32);                 \
        abuf[st][0] = *(const bf16x8*)(pa);                              \
        abuf[st][1] = *(const bf16x8*)(pa + 16 * 32);                    \
        abuf[st][2] = *(const bf16x8*)(pa + 32 * 32);                    \
        abuf[st][3] = *(const bf16x8*)(pa + 48 * 32);                    \
        const bf16* pb = bb + (size_t)(kb_) * (DIM * 32);                \
        bbuf[st][0] = *(const bf16x8*)(pb);                              \
        bbuf[st][1] = *(const bf16x8*)(pb + 16 * 32); }
#define MFMA_ST(st) {                                                    \
        _Pragma("unroll")                                                \
        for (int rt = 0; rt < 4; ++rt) {                                 \
            acc[rt][0] = __builtin_amdgcn_mfma_f32_16x16x32_bf16(abuf[st][rt], bbuf[st][0], acc[rt][0], 0, 0, 0); \
            acc[rt][1] = __builtin_amdgcn_mfma_f32_16x16x32_bf16(abuf[st][rt], bbuf[st][1], acc[rt][1], 0, 0, 0); } }

    LOAD_ST(0, 0); LOAD_ST(1, 1); LOAD_ST(2, 2); LOAD_ST(3, 3);
#pragma unroll 1
    for (int kb0 = 0; kb0 < KB2; kb0 += 4) {
        int p0 = kb0 + 4; if (p0 > 63) p0 = 63;   // tail: reload zero slab
        int p1 = kb0 + 5; if (p1 > 63) p1 = 63;
        int p2 = kb0 + 6; if (p2 > 63) p2 = 63;
        int p3 = kb0 + 7; if (p3 > 63) p3 = 63;
        MFMA_ST(0); LOAD_ST(0, p0);
        MFMA_ST(1); LOAD_ST(1, p1);
        MFMA_ST(2); LOAD_ST(2, p2);
        MFMA_ST(3); LOAD_ST(3, p3);
    }
#undef LOAD_ST
#undef MFMA_ST

    // Epilogue: C/D layout col = lane&15, row = quad*4 + reg
#pragma unroll
    for (int rt = 0; rt < 4; ++rt) {
        const int nbase = n0 + wm * 64 + rt * 16 + quad * 4;
#pragma unroll
        for (int ct = 0; ct < 2; ++ct) {
            const int c = wn * 32 + ct * 16 + l15;
#pragma unroll
            for (int r = 0; r < 4; ++r) {
                int n = nbase + r;
                if (n < N_NODES)
                    Ybf[((size_t)b * N_NODES + n) * DIM + c] = (bf16)acc[rt][ct][r];
            }
            if (write_ytp && nbase + 4 <= N_NODES) {
                bf16x4pk pk;
                pk.v[0] = (bf16)acc[rt][ct][0];
                pk.v[1] = (bf16)acc[rt][ct][1];
                pk.v[2] = (bf16)acc[rt][ct][2];
                pk.v[3] = (bf16)acc[rt][ct][3];
                const int kb2 = nbase >> 5, kk = nbase & 31;
                *(bf16x4pk*)&Ytp[((size_t)(b * KB2 + kb2) * DIM + c) * 32 + kk] = pk;
            }
        }
    }
}

// ---------------------------------------------------------------------------
// Kernel 4a: wpT2[col][d] (d pad 32) + embp[n][d] (d pad 32), bf16;
// also zero-fills the Sp kb=63 slab (A=0 makes KB2 loop exact).
// ---------------------------------------------------------------------------
#define Z0   (WCOLS * 32)
#define Z1   (Z0 + N_NODES * 32)
#define Z2   (Z1 + NP * 32)
__global__ __launch_bounds__(256) void prep_small(
    const float* __restrict__ wp, const float* __restrict__ emb,
    bf16* __restrict__ wpT2, bf16* __restrict__ embp, bf16* __restrict__ Sp63)
{
    int idx = blockIdx.x * 256 + threadIdx.x;
    if (idx < Z0) {
        int col = idx >> 5, d = idx & 31;
        int o  = col / KI;
        int kk = col - o * KI;
        int cheb = kk >> 6, i = kk & 63;
        float v = (d < EMB) ? wp[(((d * 3 + cheb) * 64 + i) * 64) + o] : 0.0f;
        wpT2[idx] = (bf16)v;
    } else if (idx < Z1) {
        int j = idx - Z0;
        int n = j >> 5, d = j & 31;
        float v = (d < EMB) ? emb[n * EMB + d] : 0.0f;
        embp[j] = (bf16)v;
    } else if (idx < Z2) {
        Sp63[idx - Z1] = (bf16)0.0f;
    }
}

// ---------------------------------------------------------------------------
// Kernel 4b: W[n][col] = sum_d embp[n][d] * wpT2[col][d]  (bf16 out)
// ---------------------------------------------------------------------------
__global__ __launch_bounds__(256) void prep_W_mfma(
    const bf16* __restrict__ embp, const bf16* __restrict__ wpT2,
    bf16* __restrict__ W)
{
    const int colbase = blockIdx.x * 256;
    const int n0      = blockIdx.y * 16;
    const int tid  = threadIdx.x;
    const int lane = tid & 63, wave = tid >> 6;
    const int l15 = lane & 15, quad = lane >> 4;

    __shared__ bf16 Cs[16][264];

    const bf16x8 af = *(const bf16x8*)&embp[(n0 + l15) * 32 + quad * 8];
    const f32x4 zero = {};
#pragma unroll
    for (int ct = 0; ct < 4; ++ct) {
        const int col = colbase + wave * 64 + ct * 16 + l15;
        bf16x8 bfr = *(const bf16x8*)&wpT2[(size_t)col * 32 + quad * 8];
        f32x4 acc = __builtin_amdgcn_mfma_f32_16x16x32_bf16(af, bfr, zero, 0, 0, 0);
#pragma unroll
        for (int r = 0; r < 4; ++r)
            Cs[quad * 4 + r][wave * 64 + ct * 16 + l15] = (bf16)acc[r];
    }
    __syncthreads();
    {
        const int row = tid >> 4;
        const int c16 = (tid & 15) * 16;
        bf16x8 v0 = *(const bf16x8*)&Cs[row][c16];
        bf16x8 v1 = *(const bf16x8*)&Cs[row][c16 + 8];
        bf16* dst = &W[(size_t)(n0 + row) * WCOLS + colbase + c16];
        *(bf16x8*)dst       = v0;
        *(bf16x8*)(dst + 8) = v1;
    }
}

// ---------------------------------------------------------------------------
// Kernel 5: per-node combine (bf16 inputs).
// ---------------------------------------------------------------------------
__global__ __launch_bounds__(256) void combine_node(
    const bf16* __restrict__ xbf, const bf16* __restrict__ y1bf,
    const bf16* __restrict__ y2bf, const float* __restrict__ emb,
    const float* __restrict__ bp, const bf16* __restrict__ W,
    float* __restrict__ out)
{
    const int n   = blockIdx.x;
    const int tid = threadIdx.x;
    const int lane = tid & 63, wave = tid >> 6;
    const int l15 = lane & 15, quad = lane >> 4;

    __shared__ bf16 As[BATCH][200];
    __shared__ bf16 Ws[DIM][200];
    __shared__ float bias_s[DIM];
    __shared__ float emb_s[EMB];

    if (tid < EMB) emb_s[tid] = emb[n * EMB + tid];

    {
        const int b  = tid >> 3;
        const int c8 = (tid & 7) * 8;
        const size_t base = ((size_t)b * N_NODES + n) * DIM + c8;
        bf16x8 vx = *(const bf16x8*)&xbf [base];
        bf16x8 v1 = *(const bf16x8*)&y1bf[base];
        bf16x8 v2 = *(const bf16x8*)&y2bf[base];
        bf16x8 p2;
#pragma unroll
        for (int e = 0; e < 8; ++e)
            p2[e] = (bf16)(2.0f * (float)v2[e] - (float)vx[e]);
        *(bf16x8*)&As[b][c8]       = vx;
        *(bf16x8*)&As[b][64 + c8]  = v1;
        *(bf16x8*)&As[b][128 + c8] = p2;
    }
    {
        const bf16* Wn = W + (size_t)n * WCOLS;
#pragma unroll
        for (int jj = 0; jj < 6; ++jj) {
            int chunk = jj * 256 + tid;
            int o  = chunk / 24;
            int kc = chunk - o * 24;
            bf16x8 v = *(const bf16x8*)&Wn[(size_t)chunk * 8];
            *(bf16x8*)&Ws[o][kc * 8] = v;
        }
    }
    __syncthreads();

    if (tid < DIM) {
        float s = 0.0f;
#pragma unroll
        for (int d = 0; d < EMB; ++d) s += emb_s[d] * bp[d * DIM + tid];
        bias_s[tid] = s;
    }

    bf16x8 af[2][6];
#pragma unroll
    for (int mt = 0; mt < 2; ++mt)
#pragma unroll
        for (int ks = 0; ks < 6; ++ks)
            af[mt][ks] = *(const bf16x8*)&As[mt * 16 + l15][ks * 32 + quad * 8];

    f32x4 acc[2] = {};
#pragma unroll
    for (int ks = 0; ks < 6; ++ks) {
        bf16x8 bfr = *(const bf16x8*)&Ws[wave * 16 + l15][ks * 32 + quad * 8];
        acc[0] = __builtin_amdgcn_mfma_f32_16x16x32_bf16(af[0][ks], bfr, acc[0], 0, 0, 0);
        acc[1] = __builtin_amdgcn_mfma_f32_16x16x32_bf16(af[1][ks], bfr, acc[1], 0, 0, 0);
    }
    __syncthreads();

    const int o = wave * 16 + l15;
    const float bv = bias_s[o];
#pragma unroll
    for (int mt = 0; mt < 2; ++mt)
#pragma unroll
        for (int r = 0; r < 4; ++r) {
            int b = mt * 16 + quad * 4 + r;
            out[((size_t)b * N_NODES + n) * DIM + o] = acc[mt][r] + bv;
        }
}

// ---------------------------------------------------------------------------
extern "C" void kernel_launch(void* const* d_in, const int* in_sizes, int n_in,
                              void* d_out, int out_size, void* d_ws, size_t ws_size,
                              hipStream_t stream) {
    const float* x   = (const float*)d_in[0];  // [32,2000,64]
    const float* emb = (const float*)d_in[1];  // [2000,16]
    const float* nv1 = (const float*)d_in[2];  // [2000,16]
    const float* nv2 = (const float*)d_in[3];  // [16,2000]
    const float* wp  = (const float*)d_in[4];  // [16,3,64,64]
    const float* bp  = (const float*)d_in[5];  // [16,64]
    float* out = (float*)d_out;                // [32,2000,64]

    char* w = (char*)d_ws;
    bf16* Sp   = (bf16*)w;  w += (size_t)KB2 * NP * 32 * 2;           //  8.39 MB
    bf16* xTp  = (bf16*)w;  w += (size_t)BATCH * KB2 * DIM * 32 * 2;  //  8.39 MB
    bf16* y1Tp = (bf16*)w;  w += (size_t)BATCH * KB2 * DIM * 32 * 2;  //  8.39 MB
    bf16* xbf  = (bf16*)w;  w += (size_t)BATCH * N_NODES * DIM * 2;   //  8.19 MB
    bf16* y1bf = (bf16*)w;  w += (size_t)BATCH * N_NODES * DIM * 2;   //  8.19 MB
    bf16* y2bf = (bf16*)w;  w += (size_t)BATCH * N_NODES * DIM * 2;   //  8.19 MB
    bf16* wpT2 = (bf16*)w;  w += (size_t)WCOLS * 32 * 2;              //  0.79 MB
    bf16* embp = (bf16*)w;  w += (size_t)N_NODES * 32 * 2;            //  0.13 MB
    bf16* W    = (bf16*)w;                                            // 49.15 MB

    adj_softmax_pack<<<N_NODES, 256, 0, stream>>>(nv1, nv2, Sp);
    transpose_pack_x<<<dim3(32, BATCH), 256, 0, stream>>>(x, xTp, xbf);
    prep_small<<<(Z2 + 255) / 256, 256, 0, stream>>>(
        wp, emb, wpT2, embp, Sp + (size_t)63 * NP * 32);
    prep_W_mfma<<<dim3(WCOLS / 256, N_NODES / 16), 256, 0, stream>>>(embp, wpT2, W);
    spmm_pack<<<dim3(16, BATCH), 256, 0, stream>>>(Sp, xTp,  y1bf, y1Tp, 1);
    spmm_pack<<<dim3(16, BATCH), 256, 0, stream>>>(Sp, y1Tp, y2bf, y1Tp, 0);
    combine_node<<<N_NODES, 256, 0, stream>>>(xbf, y1bf, y2bf, emb, bp, W, out);
}

// Round 8
// 192.934 us; speedup vs baseline: 1.1581x; 1.1581x over previous
//
#include <hip/hip_runtime.h>

#define N_NODES 2000
#define NP      2048    // Sp n-dim padding
#define KB      63      // real k-blocks (k = 2000 padded to 2016 in-block)
#define KB2     64      // loop k-blocks (kb=63 slab of Sp zero-filled)
#define BATCH   32
#define DIM     64      // DIM_IN == DIM_OUT
#define EMB     16
#define KI      192     // CHEB_K * DIM_IN
#define WCOLS   12288   // DIM_OUT * KI

typedef __bf16 bf16;
typedef __attribute__((ext_vector_type(8))) __bf16 bf16x8;
typedef __attribute__((ext_vector_type(4))) float  f32x4;

struct alignas(8) bf16x4pk { bf16 v[4]; };

// Async global->LDS DMA, 16 B per lane. No VGPR defs -> scheduler can't
// collapse the prefetch (R5-R7 failure mode for register pipelines).
__device__ __forceinline__ void gl_lds16(const bf16* g, bf16* l) {
    __builtin_amdgcn_global_load_lds(
        (__attribute__((address_space(1))) void*)(g),
        (__attribute__((address_space(3))) void*)(l), 16, 0, 0);
}

// Packed tile format (4 KB = 256 granules of 16 B), for a 64(row) x 32(k) tile:
//   granule(q, r) = q*64 + r holds elements [row=r][k = q*8 .. q*8+7]
// MFMA fragment read (lane l15, quad q) = granule q*64 + t*16 + l15 ->
// every 8-lane phase reads 8 consecutive granules -> conflict-free b128.

// ---------------------------------------------------------------------------
// Kernel 1: softmax(relu(nv1@nv2)) row -> Sp packed tiles [kb][nt][q][r][j]
// ---------------------------------------------------------------------------
__global__ __launch_bounds__(256) void adj_softmax_pack(
    const float* __restrict__ nv1, const float* __restrict__ nv2,
    bf16* __restrict__ Sp)
{
    const int row = blockIdx.x;
    const int tid = threadIdx.x;
    const int j0  = tid * 8;
    __shared__ float sa[EMB];
    __shared__ float wred[4];
    __shared__ float bcast;
    if (tid < EMB) sa[tid] = nv1[row * EMB + tid];
    __syncthreads();

    const bool active = (tid < 250);
    float v[8] = {0,0,0,0,0,0,0,0};
    if (active) {
#pragma unroll
        for (int d = 0; d < EMB; ++d) {
            const float sd = sa[d];
            const float4 q0 = *(const float4*)&nv2[d * N_NODES + j0];
            const float4 q1 = *(const float4*)&nv2[d * N_NODES + j0 + 4];
            v[0] += sd * q0.x; v[1] += sd * q0.y; v[2] += sd * q0.z; v[3] += sd * q0.w;
            v[4] += sd * q1.x; v[5] += sd * q1.y; v[6] += sd * q1.z; v[7] += sd * q1.w;
        }
    }
    float lmax = 0.0f;
#pragma unroll
    for (int jj = 0; jj < 8; ++jj) { v[jj] = fmaxf(v[jj], 0.0f); lmax = fmaxf(lmax, v[jj]); }
#pragma unroll
    for (int off = 32; off > 0; off >>= 1)
        lmax = fmaxf(lmax, __shfl_down(lmax, off, 64));
    if ((tid & 63) == 0) wred[tid >> 6] = lmax;
    __syncthreads();
    if (tid == 0) bcast = fmaxf(fmaxf(wred[0], wred[1]), fmaxf(wred[2], wred[3]));
    __syncthreads();
    const float rmax = bcast;

    float lsum = 0.0f;
    if (active) {
#pragma unroll
        for (int jj = 0; jj < 8; ++jj) { v[jj] = __expf(v[jj] - rmax); lsum += v[jj]; }
    }
#pragma unroll
    for (int off = 32; off > 0; off >>= 1)
        lsum += __shfl_down(lsum, off, 64);
    if ((tid & 63) == 0) wred[tid >> 6] = lsum;
    __syncthreads();
    if (tid == 0) bcast = wred[0] + wred[1] + wred[2] + wred[3];
    __syncthreads();
    const float inv = 1.0f / bcast;

    if (tid < 252) {   // threads 250,251 write the k 2000..2015 zero pad
        bf16x8 pk;
#pragma unroll
        for (int jj = 0; jj < 8; ++jj)
            pk[jj] = (bf16)(active ? v[jj] * inv : 0.0f);
        const int kb = j0 >> 5, q = (j0 >> 3) & 3;
        const int nt = row >> 6, r = row & 63;
        *(bf16x8*)&Sp[((size_t)(kb * 32 + nt) * 256 + q * 64 + r) * 8] = pk;
    }
}

// ---------------------------------------------------------------------------
// Kernel 2: x [b][m][c] fp32 -> xTp packed tiles [b][kb][q][c][j] bf16
//           + xbf row-major [b][m][c] bf16.
// ---------------------------------------------------------------------------
__global__ __launch_bounds__(256) void transpose_pack_x(
    const float* __restrict__ X, bf16* __restrict__ Xtp, bf16* __restrict__ Xbf)
{
    const int b  = blockIdx.y;
    const int m0 = blockIdx.x * 64;
    const int tid = threadIdx.x;
    __shared__ bf16 T[64][72];
#pragma unroll
    for (int i = 0; i < 4; ++i) {
        int idx = i * 256 + tid;
        int r  = idx >> 4;
        int c4 = (idx & 15) * 4;
        int m  = m0 + r;
        float4 v = make_float4(0.f, 0.f, 0.f, 0.f);
        if (m < N_NODES)
            v = *(const float4*)&X[((size_t)b * N_NODES + m) * DIM + c4];
        bf16x4pk pk;
        pk.v[0] = (bf16)v.x; pk.v[1] = (bf16)v.y;
        pk.v[2] = (bf16)v.z; pk.v[3] = (bf16)v.w;
        if (m < N_NODES)
            *(bf16x4pk*)&Xbf[((size_t)b * N_NODES + m) * DIM + c4] = pk;
        T[c4 + 0][r] = pk.v[0];
        T[c4 + 1][r] = pk.v[1];
        T[c4 + 2][r] = pk.v[2];
        T[c4 + 3][r] = pk.v[3];
    }
    __syncthreads();
#pragma unroll
    for (int i = 0; i < 2; ++i) {
        int idx = i * 256 + tid;       // 0..511
        int c   = idx >> 3;
        int mch = idx & 7;             // 8-elem m-chunk within the 64-m block
        int kb  = (m0 >> 5) + (mch >> 2);
        if (kb < KB) {
            int q = mch & 3;
            bf16x8 vv = *(const bf16x8*)&T[c][mch * 8];
            *(bf16x8*)&Xtp[((size_t)(b * KB2 + kb) * 256 + q * 64 + c) * 8] = vv;
        }
    }
}

// ---------------------------------------------------------------------------
// Kernel 3: spmm via single-wave workgroups + LDS-DMA 4-stage pipeline.
// One wave per 64n x 64c tile (c = one batch). Per k-block: 8 async DMA
// (issued 3 iters ahead), 8 conflict-free ds_read_b128, 16 MFMAs.
// No barriers exist (1 wave, private LDS) -> no vmcnt(0)-drain stall point.
// ---------------------------------------------------------------------------
__global__ __launch_bounds__(64) void spmm_pack(
    const bf16* __restrict__ Ap, const bf16* __restrict__ Btp,
    bf16* __restrict__ Ybf, bf16* __restrict__ Ytp, int write_ytp)
{
    const int nt = blockIdx.x;
    const int b  = blockIdx.y;
    const int n0 = nt * 64;
    const int lane = threadIdx.x;       // 0..63
    const int l15 = lane & 15, quad = lane >> 4;

    __shared__ bf16 sta[4][2048];   // 4 stages x 4 KB A-tile
    __shared__ bf16 stb[4][2048];   // 4 stages x 4 KB B-tile

    const bf16* asrc = Ap  + (size_t)nt * 2048 + lane * 8;        // + kb*32*2048
    const bf16* bsrc = Btp + (size_t)(b * KB2) * 2048 + lane * 8; // + kb*2048

#define DMA_STAGE(st, kb_) {                                         \
        const bf16* pa = asrc + (size_t)(kb_) * (32 * 2048);         \
        const bf16* pb = bsrc + (size_t)(kb_) * 2048;                \
        gl_lds16(pa,        &sta[st][lane * 8]);                     \
        gl_lds16(pa + 512,  &sta[st][ 512 + lane * 8]);              \
        gl_lds16(pa + 1024, &sta[st][1024 + lane * 8]);              \
        gl_lds16(pa + 1536, &sta[st][1536 + lane * 8]);              \
        gl_lds16(pb,        &stb[st][lane * 8]);                     \
        gl_lds16(pb + 512,  &stb[st][ 512 + lane * 8]);              \
        gl_lds16(pb + 1024, &stb[st][1024 + lane * 8]);              \
        gl_lds16(pb + 1536, &stb[st][1536 + lane * 8]); }

    f32x4 acc[4][4] = {};

    DMA_STAGE(0, 0); DMA_STAGE(1, 1); DMA_STAGE(2, 2);

#pragma unroll 1
    for (int kb = 0; kb < KB2; ++kb) {
        const int s = kb & 3;
        bf16x8 af[4], bfr[4];
#pragma unroll
        for (int t = 0; t < 4; ++t)
            af[t]  = *(const bf16x8*)&sta[s][(quad * 64 + t * 16 + l15) * 8];
#pragma unroll
        for (int t = 0; t < 4; ++t)
            bfr[t] = *(const bf16x8*)&stb[s][(quad * 64 + t * 16 + l15) * 8];
        if (kb < KB2 - 3) DMA_STAGE((kb + 3) & 3, kb + 3);
#pragma unroll
        for (int rt = 0; rt < 4; ++rt)
#pragma unroll
            for (int ct = 0; ct < 4; ++ct)
                acc[rt][ct] = __builtin_amdgcn_mfma_f32_16x16x32_bf16(
                    af[rt], bfr[ct], acc[rt][ct], 0, 0, 0);
    }
#undef DMA_STAGE

    // Epilogue. C/D layout: col = lane&15, row = quad*4 + reg
#pragma unroll
    for (int rt = 0; rt < 4; ++rt) {
        const int nbase = n0 + rt * 16 + quad * 4;
#pragma unroll
        for (int ct = 0; ct < 4; ++ct) {
            const int c = ct * 16 + l15;
#pragma unroll
            for (int r = 0; r < 4; ++r) {
                int n = nbase + r;
                if (n < N_NODES)
                    Ybf[((size_t)b * N_NODES + n) * DIM + c] = (bf16)acc[rt][ct][r];
            }
            if (write_ytp && nbase + 4 <= N_NODES) {
                const int kb2 = nbase >> 5;
                const int m5  = nbase & 31;
                const int kq  = m5 >> 3;
                const int j4  = m5 & 7;          // 0 or 4
                bf16x4pk pk;
                pk.v[0] = (bf16)acc[rt][ct][0];
                pk.v[1] = (bf16)acc[rt][ct][1];
                pk.v[2] = (bf16)acc[rt][ct][2];
                pk.v[3] = (bf16)acc[rt][ct][3];
                *(bf16x4pk*)&Ytp[((size_t)(b * KB2 + kb2) * 256 + kq * 64 + c) * 8 + j4] = pk;
            }
        }
    }
}

// ---------------------------------------------------------------------------
// Kernel 4a: wpT2[col][d] (d pad 32) + embp[n][d] (d pad 32), bf16;
// also zero-fills the Sp kb=63 slab (same address range as before).
// ---------------------------------------------------------------------------
#define Z0   (WCOLS * 32)
#define Z1   (Z0 + N_NODES * 32)
#define Z2   (Z1 + NP * 32)
__global__ __launch_bounds__(256) void prep_small(
    const float* __restrict__ wp, const float* __restrict__ emb,
    bf16* __restrict__ wpT2, bf16* __restrict__ embp, bf16* __restrict__ Sp63)
{
    int idx = blockIdx.x * 256 + threadIdx.x;
    if (idx < Z0) {
        int col = idx >> 5, d = idx & 31;
        int o  = col / KI;
        int kk = col - o * KI;
        int cheb = kk >> 6, i = kk & 63;
        float v = (d < EMB) ? wp[(((d * 3 + cheb) * 64 + i) * 64) + o] : 0.0f;
        wpT2[idx] = (bf16)v;
    } else if (idx < Z1) {
        int j = idx - Z0;
        int n = j >> 5, d = j & 31;
        float v = (d < EMB) ? emb[n * EMB + d] : 0.0f;
        embp[j] = (bf16)v;
    } else if (idx < Z2) {
        Sp63[idx - Z1] = (bf16)0.0f;
    }
}

// ---------------------------------------------------------------------------
// Kernel 4b: W[n][col] = sum_d embp[n][d] * wpT2[col][d]  (bf16 out)
// ---------------------------------------------------------------------------
__global__ __launch_bounds__(256) void prep_W_mfma(
    const bf16* __restrict__ embp, const bf16* __restrict__ wpT2,
    bf16* __restrict__ W)
{
    const int colbase = blockIdx.x * 256;
    const int n0      = blockIdx.y * 16;
    const int tid  = threadIdx.x;
    const int lane = tid & 63, wave = tid >> 6;
    const int l15 = lane & 15, quad = lane >> 4;

    __shared__ bf16 Cs[16][264];

    const bf16x8 af = *(const bf16x8*)&embp[(n0 + l15) * 32 + quad * 8];
    const f32x4 zero = {};
#pragma unroll
    for (int ct = 0; ct < 4; ++ct) {
        const int col = colbase + wave * 64 + ct * 16 + l15;
        bf16x8 bfr = *(const bf16x8*)&wpT2[(size_t)col * 32 + quad * 8];
        f32x4 acc = __builtin_amdgcn_mfma_f32_16x16x32_bf16(af, bfr, zero, 0, 0, 0);
#pragma unroll
        for (int r = 0; r < 4; ++r)
            Cs[quad * 4 + r][wave * 64 + ct * 16 + l15] = (bf16)acc[r];
    }
    __syncthreads();
    {
        const int row = tid >> 4;
        const int c16 = (tid & 15) * 16;
        bf16x8 v0 = *(const bf16x8*)&Cs[row][c16];
        bf16x8 v1 = *(const bf16x8*)&Cs[row][c16 + 8];
        bf16* dst = &W[(size_t)(n0 + row) * WCOLS + colbase + c16];
        *(bf16x8*)dst       = v0;
        *(bf16x8*)(dst + 8) = v1;
    }
}

// ---------------------------------------------------------------------------
// Kernel 5: per-node combine (bf16 inputs).
// ---------------------------------------------------------------------------
__global__ __launch_bounds__(256) void combine_node(
    const bf16* __restrict__ xbf, const bf16* __restrict__ y1bf,
    const bf16* __restrict__ y2bf, const float* __restrict__ emb,
    const float* __restrict__ bp, const bf16* __restrict__ W,
    float* __restrict__ out)
{
    const int n   = blockIdx.x;
    const int tid = threadIdx.x;
    const int lane = tid & 63, wave = tid >> 6;
    const int l15 = lane & 15, quad = lane >> 4;

    __shared__ bf16 As[BATCH][200];
    __shared__ bf16 Ws[DIM][200];
    __shared__ float bias_s[DIM];
    __shared__ float emb_s[EMB];

    if (tid < EMB) emb_s[tid] = emb[n * EMB + tid];

    {
        const int b  = tid >> 3;
        const int c8 = (tid & 7) * 8;
        const size_t base = ((size_t)b * N_NODES + n) * DIM + c8;
        bf16x8 vx = *(const bf16x8*)&xbf [base];
        bf16x8 v1 = *(const bf16x8*)&y1bf[base];
        bf16x8 v2 = *(const bf16x8*)&y2bf[base];
        bf16x8 p2;
#pragma unroll
        for (int e = 0; e < 8; ++e)
            p2[e] = (bf16)(2.0f * (float)v2[e] - (float)vx[e]);
        *(bf16x8*)&As[b][c8]       = vx;
        *(bf16x8*)&As[b][64 + c8]  = v1;
        *(bf16x8*)&As[b][128 + c8] = p2;
    }
    {
        const bf16* Wn = W + (size_t)n * WCOLS;
#pragma unroll
        for (int jj = 0; jj < 6; ++jj) {
            int chunk = jj * 256 + tid;
            int o  = chunk / 24;
            int kc = chunk - o * 24;
            bf16x8 v = *(const bf16x8*)&Wn[(size_t)chunk * 8];
            *(bf16x8*)&Ws[o][kc * 8] = v;
        }
    }
    __syncthreads();

    if (tid < DIM) {
        float s = 0.0f;
#pragma unroll
        for (int d = 0; d < EMB; ++d) s += emb_s[d] * bp[d * DIM + tid];
        bias_s[tid] = s;
    }

    bf16x8 af[2][6];
#pragma unroll
    for (int mt = 0; mt < 2; ++mt)
#pragma unroll
        for (int ks = 0; ks < 6; ++ks)
            af[mt][ks] = *(const bf16x8*)&As[mt * 16 + l15][ks * 32 + quad * 8];

    f32x4 acc[2] = {};
#pragma unroll
    for (int ks = 0; ks < 6; ++ks) {
        bf16x8 bfr = *(const bf16x8*)&Ws[wave * 16 + l15][ks * 32 + quad * 8];
        acc[0] = __builtin_amdgcn_mfma_f32_16x16x32_bf16(af[0][ks], bfr, acc[0], 0, 0, 0);
        acc[1] = __builtin_amdgcn_mfma_f32_16x16x32_bf16(af[1][ks], bfr, acc[1], 0, 0, 0);
    }
    __syncthreads();

    const int o = wave * 16 + l15;
    const float bv = bias_s[o];
#pragma unroll
    for (int mt = 0; mt < 2; ++mt)
#pragma unroll
        for (int r = 0; r < 4; ++r) {
            int b = mt * 16 + quad * 4 + r;
            out[((size_t)b * N_NODES + n) * DIM + o] = acc[mt][r] + bv;
        }
}

// ---------------------------------------------------------------------------
extern "C" void kernel_launch(void* const* d_in, const int* in_sizes, int n_in,
                              void* d_out, int out_size, void* d_ws, size_t ws_size,
                              hipStream_t stream) {
    const float* x   = (const float*)d_in[0];  // [32,2000,64]
    const float* emb = (const float*)d_in[1];  // [2000,16]
    const float* nv1 = (const float*)d_in[2];  // [2000,16]
    const float* nv2 = (const float*)d_in[3];  // [16,2000]
    const float* wp  = (const float*)d_in[4];  // [16,3,64,64]
    const float* bp  = (const float*)d_in[5];  // [16,64]
    float* out = (float*)d_out;                // [32,2000,64]

    char* w = (char*)d_ws;
    bf16* Sp   = (bf16*)w;  w += (size_t)KB2 * NP * 32 * 2;           //  8.39 MB
    bf16* xTp  = (bf16*)w;  w += (size_t)BATCH * KB2 * DIM * 32 * 2;  //  8.39 MB
    bf16* y1Tp = (bf16*)w;  w += (size_t)BATCH * KB2 * DIM * 32 * 2;  //  8.39 MB
    bf16* xbf  = (bf16*)w;  w += (size_t)BATCH * N_NODES * DIM * 2;   //  8.19 MB
    bf16* y1bf = (bf16*)w;  w += (size_t)BATCH * N_NODES * DIM * 2;   //  8.19 MB
    bf16* y2bf = (bf16*)w;  w += (size_t)BATCH * N_NODES * DIM * 2;   //  8.19 MB
    bf16* wpT2 = (bf16*)w;  w += (size_t)WCOLS * 32 * 2;              //  0.79 MB
    bf16* embp = (bf16*)w;  w += (size_t)N_NODES * 32 * 2;            //  0.13 MB
    bf16* W    = (bf16*)w;                                            // 49.15 MB

    adj_softmax_pack<<<N_NODES, 256, 0, stream>>>(nv1, nv2, Sp);
    transpose_pack_x<<<dim3(32, BATCH), 256, 0, stream>>>(x, xTp, xbf);
    prep_small<<<(Z2 + 255) / 256, 256, 0, stream>>>(
        wp, emb, wpT2, embp, Sp + (size_t)63 * NP * 32);
    prep_W_mfma<<<dim3(WCOLS / 256, N_NODES / 16), 256, 0, stream>>>(embp, wpT2, W);
    spmm_pack<<<dim3(32, BATCH), 64, 0, stream>>>(Sp, xTp,  y1bf, y1Tp, 1);
    spmm_pack<<<dim3(32, BATCH), 64, 0, stream>>>(Sp, y1Tp, y2bf, y1Tp, 0);
    combine_node<<<N_NODES, 256, 0, stream>>>(xbf, y1bf, y2bf, emb, bp, W, out);
}

// Round 9
// 191.009 us; speedup vs baseline: 1.1697x; 1.0101x over previous
//
#include <hip/hip_runtime.h>

#define N_NODES 2000
#define NP      2048    // Sp n-dim padding
#define KB      63      // real k-blocks (k = 2000 padded to 2016 in-block)
#define KB2     64      // loop k-blocks (kb=63 slab of Sp zero-filled)
#define BATCH   32
#define DIM     64      // DIM_IN == DIM_OUT
#define EMB     16
#define KI      192     // CHEB_K * DIM_IN
#define WCOLS   12288   // DIM_OUT * KI

typedef __bf16 bf16;
typedef __attribute__((ext_vector_type(8))) __bf16 bf16x8;
typedef __attribute__((ext_vector_type(4))) float  f32x4;

struct alignas(8) bf16x4pk { bf16 v[4]; };

// Async global->LDS DMA, 16 B per lane (lane-contiguous within each wave).
__device__ __forceinline__ void gl_lds16(const bf16* g, bf16* l) {
    __builtin_amdgcn_global_load_lds(
        (__attribute__((address_space(1))) void*)(g),
        (__attribute__((address_space(3))) void*)(l), 16, 0, 0);
}

// Packed tile format (4 KB = 256 granules of 16 B) for a 64(row) x 32(k) tile:
//   granule(q, r) = q*64 + r holds elements [row=r][k = q*8 .. q*8+7]
// Fragment read (lane l15, quad) = granule quad*64 + t*16 + l15: 16 consecutive
// granules per quad-phase -> conflict-free ds_read_b128 (R8: 0 conflicts).

// ---------------------------------------------------------------------------
// Kernel 1: softmax(relu(nv1@nv2)) row -> Sp packed tiles [kb][nt][q][r][j]
// ---------------------------------------------------------------------------
__global__ __launch_bounds__(256) void adj_softmax_pack(
    const float* __restrict__ nv1, const float* __restrict__ nv2,
    bf16* __restrict__ Sp)
{
    const int row = blockIdx.x;
    const int tid = threadIdx.x;
    const int j0  = tid * 8;
    __shared__ float sa[EMB];
    __shared__ float wred[4];
    __shared__ float bcast;
    if (tid < EMB) sa[tid] = nv1[row * EMB + tid];
    __syncthreads();

    const bool active = (tid < 250);
    float v[8] = {0,0,0,0,0,0,0,0};
    if (active) {
#pragma unroll
        for (int d = 0; d < EMB; ++d) {
            const float sd = sa[d];
            const float4 q0 = *(const float4*)&nv2[d * N_NODES + j0];
            const float4 q1 = *(const float4*)&nv2[d * N_NODES + j0 + 4];
            v[0] += sd * q0.x; v[1] += sd * q0.y; v[2] += sd * q0.z; v[3] += sd * q0.w;
            v[4] += sd * q1.x; v[5] += sd * q1.y; v[6] += sd * q1.z; v[7] += sd * q1.w;
        }
    }
    float lmax = 0.0f;
#pragma unroll
    for (int jj = 0; jj < 8; ++jj) { v[jj] = fmaxf(v[jj], 0.0f); lmax = fmaxf(lmax, v[jj]); }
#pragma unroll
    for (int off = 32; off > 0; off >>= 1)
        lmax = fmaxf(lmax, __shfl_down(lmax, off, 64));
    if ((tid & 63) == 0) wred[tid >> 6] = lmax;
    __syncthreads();
    if (tid == 0) bcast = fmaxf(fmaxf(wred[0], wred[1]), fmaxf(wred[2], wred[3]));
    __syncthreads();
    const float rmax = bcast;

    float lsum = 0.0f;
    if (active) {
#pragma unroll
        for (int jj = 0; jj < 8; ++jj) { v[jj] = __expf(v[jj] - rmax); lsum += v[jj]; }
    }
#pragma unroll
    for (int off = 32; off > 0; off >>= 1)
        lsum += __shfl_down(lsum, off, 64);
    if ((tid & 63) == 0) wred[tid >> 6] = lsum;
    __syncthreads();
    if (tid == 0) bcast = wred[0] + wred[1] + wred[2] + wred[3];
    __syncthreads();
    const float inv = 1.0f / bcast;

    if (tid < 252) {   // threads 250,251 write the k 2000..2015 zero pad
        bf16x8 pk;
#pragma unroll
        for (int jj = 0; jj < 8; ++jj)
            pk[jj] = (bf16)(active ? v[jj] * inv : 0.0f);
        const int kb = j0 >> 5, q = (j0 >> 3) & 3;
        const int nt = row >> 6, r = row & 63;
        *(bf16x8*)&Sp[((size_t)(kb * 32 + nt) * 256 + q * 64 + r) * 8] = pk;
    }
}

// ---------------------------------------------------------------------------
// Kernel 2: x [b][m][c] fp32 -> xTp packed tiles [b][kb][q][c][j] bf16
//           + xbf row-major [b][m][c] bf16.
// ---------------------------------------------------------------------------
__global__ __launch_bounds__(256) void transpose_pack_x(
    const float* __restrict__ X, bf16* __restrict__ Xtp, bf16* __restrict__ Xbf)
{
    const int b  = blockIdx.y;
    const int m0 = blockIdx.x * 64;
    const int tid = threadIdx.x;
    __shared__ bf16 T[64][72];
#pragma unroll
    for (int i = 0; i < 4; ++i) {
        int idx = i * 256 + tid;
        int r  = idx >> 4;
        int c4 = (idx & 15) * 4;
        int m  = m0 + r;
        float4 v = make_float4(0.f, 0.f, 0.f, 0.f);
        if (m < N_NODES)
            v = *(const float4*)&X[((size_t)b * N_NODES + m) * DIM + c4];
        bf16x4pk pk;
        pk.v[0] = (bf16)v.x; pk.v[1] = (bf16)v.y;
        pk.v[2] = (bf16)v.z; pk.v[3] = (bf16)v.w;
        if (m < N_NODES)
            *(bf16x4pk*)&Xbf[((size_t)b * N_NODES + m) * DIM + c4] = pk;
        T[c4 + 0][r] = pk.v[0];
        T[c4 + 1][r] = pk.v[1];
        T[c4 + 2][r] = pk.v[2];
        T[c4 + 3][r] = pk.v[3];
    }
    __syncthreads();
#pragma unroll
    for (int i = 0; i < 2; ++i) {
        int idx = i * 256 + tid;       // 0..511
        int c   = idx >> 3;
        int mch = idx & 7;             // 8-elem m-chunk within the 64-m block
        int kb  = (m0 >> 5) + (mch >> 2);
        if (kb < KB) {
            int q = mch & 3;
            bf16x8 vv = *(const bf16x8*)&T[c][mch * 8];
            *(bf16x8*)&Xtp[((size_t)(b * KB2 + kb) * 256 + q * 64 + c) * 8] = vv;
        }
    }
}

// ---------------------------------------------------------------------------
// Kernel 3: spmm, m97-anchored multi-wave block with overlap-ordered K-loop.
// Block = 128n x 64c (one batch), 4 waves (each 32n x 64c, 2x4 MFMAs/iter).
// Double-buffered LDS (2 x 12 KB). Per iter: barrier(drain prev DMA) ->
// ds_read frags (no DMAs outstanding -> no conservative vmcnt) -> issue
// DMA for kb+1 -> MFMAs. Exposed stall ~ latency - compute; 2 blocks/CU
// (8 waves/CU) overlap each other's drains.
// ---------------------------------------------------------------------------
__global__ __launch_bounds__(256, 2) void spmm_pack(
    const bf16* __restrict__ Ap, const bf16* __restrict__ Btp,
    bf16* __restrict__ Ybf, bf16* __restrict__ Ytp, int write_ytp)
{
    const int ntB = blockIdx.x;          // 0..15 (fastest -> XCD = ntB % 8)
    const int b   = blockIdx.y;
    const int n0  = ntB * 128;
    const int tid = threadIdx.x;
    const int lane = tid & 63, wave = tid >> 6;
    const int l15 = lane & 15, quad = lane >> 4;

    __shared__ bf16 As[2][4096];   // 8 KB per buffer (128 rows x 32 k)
    __shared__ bf16 Bs[2][2048];   // 4 KB per buffer ( 64 cols x 32 k)

    const bf16* aslab = Ap  + (size_t)(ntB * 2) * 2048 + tid * 8;  // + kb*32*2048
    const bf16* bslab = Btp + (size_t)(b * KB2) * 2048 + tid * 8;  // + kb*2048

#define DMA_KB(buf, kb_) {                                           \
        const bf16* pa = aslab + (size_t)(kb_) * (32 * 2048);        \
        const bf16* pb = bslab + (size_t)(kb_) * 2048;               \
        gl_lds16(pa,        &As[buf][tid * 8]);                      \
        gl_lds16(pa + 2048, &As[buf][2048 + tid * 8]);               \
        gl_lds16(pb,        &Bs[buf][tid * 8]);  }

    f32x4 acc[2][4] = {};
    const int ga = (wave >> 1) * 256 + quad * 64 + (wave & 1) * 32; // A granule base
    const int gb = quad * 64;                                       // B granule base

    DMA_KB(0, 0);
#pragma unroll 1
    for (int kb = 0; kb < KB2; ++kb) {
        const int cur = kb & 1;
        __syncthreads();               // drains vmcnt(0): buf[cur] ready
        bf16x8 af[2], bfr[4];
#pragma unroll
        for (int t = 0; t < 2; ++t)
            af[t]  = *(const bf16x8*)&As[cur][(ga + t * 16 + l15) * 8];
#pragma unroll
        for (int t = 0; t < 4; ++t)
            bfr[t] = *(const bf16x8*)&Bs[cur][(gb + t * 16 + l15) * 8];
        if (kb + 1 < KB2) DMA_KB(cur ^ 1, kb + 1);
#pragma unroll
        for (int rt = 0; rt < 2; ++rt)
#pragma unroll
            for (int ct = 0; ct < 4; ++ct)
                acc[rt][ct] = __builtin_amdgcn_mfma_f32_16x16x32_bf16(
                    af[rt], bfr[ct], acc[rt][ct], 0, 0, 0);
    }
#undef DMA_KB

    // Epilogue. C/D layout: col = lane&15, row = quad*4 + reg
#pragma unroll
    for (int rt = 0; rt < 2; ++rt) {
        const int nbase = n0 + wave * 32 + rt * 16 + quad * 4;
#pragma unroll
        for (int ct = 0; ct < 4; ++ct) {
            const int c = ct * 16 + l15;
#pragma unroll
            for (int r = 0; r < 4; ++r) {
                int n = nbase + r;
                if (n < N_NODES)
                    Ybf[((size_t)b * N_NODES + n) * DIM + c] = (bf16)acc[rt][ct][r];
            }
            if (write_ytp && nbase + 4 <= N_NODES) {
                const int kb2 = nbase >> 5;
                const int kq  = (nbase & 31) >> 3;
                const int j4  = nbase & 7;       // 0 or 4
                bf16x4pk pk;
                pk.v[0] = (bf16)acc[rt][ct][0];
                pk.v[1] = (bf16)acc[rt][ct][1];
                pk.v[2] = (bf16)acc[rt][ct][2];
                pk.v[3] = (bf16)acc[rt][ct][3];
                *(bf16x4pk*)&Ytp[((size_t)(b * KB2 + kb2) * 256 + kq * 64 + c) * 8 + j4] = pk;
            }
        }
    }
}

// ---------------------------------------------------------------------------
// Kernel 4a: wpT2[col][d] (d pad 32) + embp[n][d] (d pad 32), bf16;
// also zero-fills the Sp kb=63 slab.
// ---------------------------------------------------------------------------
#define Z0   (WCOLS * 32)
#define Z1   (Z0 + N_NODES * 32)
#define Z2   (Z1 + NP * 32)
__global__ __launch_bounds__(256) void prep_small(
    const float* __restrict__ wp, const float* __restrict__ emb,
    bf16* __restrict__ wpT2, bf16* __restrict__ embp, bf16* __restrict__ Sp63)
{
    int idx = blockIdx.x * 256 + threadIdx.x;
    if (idx < Z0) {
        int col = idx >> 5, d = idx & 31;
        int o  = col / KI;
        int kk = col - o * KI;
        int cheb = kk >> 6, i = kk & 63;
        float v = (d < EMB) ? wp[(((d * 3 + cheb) * 64 + i) * 64) + o] : 0.0f;
        wpT2[idx] = (bf16)v;
    } else if (idx < Z1) {
        int j = idx - Z0;
        int n = j >> 5, d = j & 31;
        float v = (d < EMB) ? emb[n * EMB + d] : 0.0f;
        embp[j] = (bf16)v;
    } else if (idx < Z2) {
        Sp63[idx - Z1] = (bf16)0.0f;
    }
}

// ---------------------------------------------------------------------------
// Kernel 4b: W[n][col] = sum_d embp[n][d] * wpT2[col][d]  (bf16 out)
// ---------------------------------------------------------------------------
__global__ __launch_bounds__(256) void prep_W_mfma(
    const bf16* __restrict__ embp, const bf16* __restrict__ wpT2,
    bf16* __restrict__ W)
{
    const int colbase = blockIdx.x * 256;
    const int n0      = blockIdx.y * 16;
    const int tid  = threadIdx.x;
    const int lane = tid & 63, wave = tid >> 6;
    const int l15 = lane & 15, quad = lane >> 4;

    __shared__ bf16 Cs[16][264];

    const bf16x8 af = *(const bf16x8*)&embp[(n0 + l15) * 32 + quad * 8];
    const f32x4 zero = {};
#pragma unroll
    for (int ct = 0; ct < 4; ++ct) {
        const int col = colbase + wave * 64 + ct * 16 + l15;
        bf16x8 bfr = *(const bf16x8*)&wpT2[(size_t)col * 32 + quad * 8];
        f32x4 acc = __builtin_amdgcn_mfma_f32_16x16x32_bf16(af, bfr, zero, 0, 0, 0);
#pragma unroll
        for (int r = 0; r < 4; ++r)
            Cs[quad * 4 + r][wave * 64 + ct * 16 + l15] = (bf16)acc[r];
    }
    __syncthreads();
    {
        const int row = tid >> 4;
        const int c16 = (tid & 15) * 16;
        bf16x8 v0 = *(const bf16x8*)&Cs[row][c16];
        bf16x8 v1 = *(const bf16x8*)&Cs[row][c16 + 8];
        bf16* dst = &W[(size_t)(n0 + row) * WCOLS + colbase + c16];
        *(bf16x8*)dst       = v0;
        *(bf16x8*)(dst + 8) = v1;
    }
}

// ---------------------------------------------------------------------------
// Kernel 5: per-node combine (bf16 inputs).
// ---------------------------------------------------------------------------
__global__ __launch_bounds__(256) void combine_node(
    const bf16* __restrict__ xbf, const bf16* __restrict__ y1bf,
    const bf16* __restrict__ y2bf, const float* __restrict__ emb,
    const float* __restrict__ bp, const bf16* __restrict__ W,
    float* __restrict__ out)
{
    const int n   = blockIdx.x;
    const int tid = threadIdx.x;
    const int lane = tid & 63, wave = tid >> 6;
    const int l15 = lane & 15, quad = lane >> 4;

    __shared__ bf16 As[BATCH][200];
    __shared__ bf16 Ws[DIM][200];
    __shared__ float bias_s[DIM];
    __shared__ float emb_s[EMB];

    if (tid < EMB) emb_s[tid] = emb[n * EMB + tid];

    {
        const int b  = tid >> 3;
        const int c8 = (tid & 7) * 8;
        const size_t base = ((size_t)b * N_NODES + n) * DIM + c8;
        bf16x8 vx = *(const bf16x8*)&xbf [base];
        bf16x8 v1 = *(const bf16x8*)&y1bf[base];
        bf16x8 v2 = *(const bf16x8*)&y2bf[base];
        bf16x8 p2;
#pragma unroll
        for (int e = 0; e < 8; ++e)
            p2[e] = (bf16)(2.0f * (float)v2[e] - (float)vx[e]);
        *(bf16x8*)&As[b][c8]       = vx;
        *(bf16x8*)&As[b][64 + c8]  = v1;
        *(bf16x8*)&As[b][128 + c8] = p2;
    }
    {
        const bf16* Wn = W + (size_t)n * WCOLS;
#pragma unroll
        for (int jj = 0; jj < 6; ++jj) {
            int chunk = jj * 256 + tid;
            int o  = chunk / 24;
            int kc = chunk - o * 24;
            bf16x8 v = *(const bf16x8*)&Wn[(size_t)chunk * 8];
            *(bf16x8*)&Ws[o][kc * 8] = v;
        }
    }
    __syncthreads();

    if (tid < DIM) {
        float s = 0.0f;
#pragma unroll
        for (int d = 0; d < EMB; ++d) s += emb_s[d] * bp[d * DIM + tid];
        bias_s[tid] = s;
    }

    bf16x8 af[2][6];
#pragma unroll
    for (int mt = 0; mt < 2; ++mt)
#pragma unroll
        for (int ks = 0; ks < 6; ++ks)
            af[mt][ks] = *(const bf16x8*)&As[mt * 16 + l15][ks * 32 + quad * 8];

    f32x4 acc[2] = {};
#pragma unroll
    for (int ks = 0; ks < 6; ++ks) {
        bf16x8 bfr = *(const bf16x8*)&Ws[wave * 16 + l15][ks * 32 + quad * 8];
        acc[0] = __builtin_amdgcn_mfma_f32_16x16x32_bf16(af[0][ks], bfr, acc[0], 0, 0, 0);
        acc[1] = __builtin_amdgcn_mfma_f32_16x16x32_bf16(af[1][ks], bfr, acc[1], 0, 0, 0);
    }
    __syncthreads();

    const int o = wave * 16 + l15;
    const float bv = bias_s[o];
#pragma unroll
    for (int mt = 0; mt < 2; ++mt)
#pragma unroll
        for (int r = 0; r < 4; ++r) {
            int b = mt * 16 + quad * 4 + r;
            out[((size_t)b * N_NODES + n) * DIM + o] = acc[mt][r] + bv;
        }
}

// ---------------------------------------------------------------------------
extern "C" void kernel_launch(void* const* d_in, const int* in_sizes, int n_in,
                              void* d_out, int out_size, void* d_ws, size_t ws_size,
                              hipStream_t stream) {
    const float* x   = (const float*)d_in[0];  // [32,2000,64]
    const float* emb = (const float*)d_in[1];  // [2000,16]
    const float* nv1 = (const float*)d_in[2];  // [2000,16]
    const float* nv2 = (const float*)d_in[3];  // [16,2000]
    const float* wp  = (const float*)d_in[4];  // [16,3,64,64]
    const float* bp  = (const float*)d_in[5];  // [16,64]
    float* out = (float*)d_out;                // [32,2000,64]

    char* w = (char*)d_ws;
    bf16* Sp   = (bf16*)w;  w += (size_t)KB2 * NP * 32 * 2;           //  8.39 MB
    bf16* xTp  = (bf16*)w;  w += (size_t)BATCH * KB2 * DIM * 32 * 2;  //  8.39 MB
    bf16* y1Tp = (bf16*)w;  w += (size_t)BATCH * KB2 * DIM * 32 * 2;  //  8.39 MB
    bf16* xbf  = (bf16*)w;  w += (size_t)BATCH * N_NODES * DIM * 2;   //  8.19 MB
    bf16* y1bf = (bf16*)w;  w += (size_t)BATCH * N_NODES * DIM * 2;   //  8.19 MB
    bf16* y2bf = (bf16*)w;  w += (size_t)BATCH * N_NODES * DIM * 2;   //  8.19 MB
    bf16* wpT2 = (bf16*)w;  w += (size_t)WCOLS * 32 * 2;              //  0.79 MB
    bf16* embp = (bf16*)w;  w += (size_t)N_NODES * 32 * 2;            //  0.13 MB
    bf16* W    = (bf16*)w;                                            // 49.15 MB

    adj_softmax_pack<<<N_NODES, 256, 0, stream>>>(nv1, nv2, Sp);
    transpose_pack_x<<<dim3(32, BATCH), 256, 0, stream>>>(x, xTp, xbf);
    prep_small<<<(Z2 + 255) / 256, 256, 0, stream>>>(
        wp, emb, wpT2, embp, Sp + (size_t)63 * NP * 32);
    prep_W_mfma<<<dim3(WCOLS / 256, N_NODES / 16), 256, 0, stream>>>(embp, wpT2, W);
    spmm_pack<<<dim3(16, BATCH), 256, 0, stream>>>(Sp, xTp,  y1bf, y1Tp, 1);
    spmm_pack<<<dim3(16, BATCH), 256, 0, stream>>>(Sp, y1Tp, y2bf, y1Tp, 0);
    combine_node<<<N_NODES, 256, 0, stream>>>(xbf, y1bf, y2bf, emb, bp, W, out);
}

// Round 10
// 174.238 us; speedup vs baseline: 1.2823x; 1.0963x over previous
//
#include <hip/hip_runtime.h>

#define N_NODES 2000
#define NP      2048    // Sp n-dim padding
#define KB      63      // real k-blocks (k = 2000 padded to 2016 in-block)
#define KB3     66      // padded k-blocks: slabs 63..65 of Sp zero-filled (A=0)
#define BATCH   32
#define DIM     64      // DIM_IN == DIM_OUT
#define EMB     16
#define KI      192     // CHEB_K * DIM_IN
#define WCOLS   12288   // DIM_OUT * KI

typedef __bf16 bf16;
typedef __attribute__((ext_vector_type(8))) __bf16 bf16x8;
typedef __attribute__((ext_vector_type(4))) float  f32x4;

struct alignas(8) bf16x4pk { bf16 v[4]; };

// Async global->LDS DMA, 16 B per lane (lane-contiguous within each wave).
__device__ __forceinline__ void gl_lds16(const bf16* g, bf16* l) {
    __builtin_amdgcn_global_load_lds(
        (__attribute__((address_space(1))) void*)(g),
        (__attribute__((address_space(3))) void*)(l), 16, 0, 0);
}

// Packed tile format (4 KB = 256 granules of 16 B) for a 64(row) x 32(k) tile:
//   granule(q, r) = q*64 + r holds elements [row=r][k = q*8 .. q*8+7]
// Fragment read (lane l15, quad) hits 16 consecutive granules per quad-phase
// -> conflict-free ds_read_b128 (R8/R9: SQ_LDS_BANK_CONFLICT == 0).

// ---------------------------------------------------------------------------
// Kernel 1: softmax(relu(nv1@nv2)) row -> Sp packed tiles [kb][nt][q][r][j]
// ---------------------------------------------------------------------------
__global__ __launch_bounds__(256) void adj_softmax_pack(
    const float* __restrict__ nv1, const float* __restrict__ nv2,
    bf16* __restrict__ Sp)
{
    const int row = blockIdx.x;
    const int tid = threadIdx.x;
    const int j0  = tid * 8;
    __shared__ float sa[EMB];
    __shared__ float wred[4];
    __shared__ float bcast;
    if (tid < EMB) sa[tid] = nv1[row * EMB + tid];
    __syncthreads();

    const bool active = (tid < 250);
    float v[8] = {0,0,0,0,0,0,0,0};
    if (active) {
#pragma unroll
        for (int d = 0; d < EMB; ++d) {
            const float sd = sa[d];
            const float4 q0 = *(const float4*)&nv2[d * N_NODES + j0];
            const float4 q1 = *(const float4*)&nv2[d * N_NODES + j0 + 4];
            v[0] += sd * q0.x; v[1] += sd * q0.y; v[2] += sd * q0.z; v[3] += sd * q0.w;
            v[4] += sd * q1.x; v[5] += sd * q1.y; v[6] += sd * q1.z; v[7] += sd * q1.w;
        }
    }
    float lmax = 0.0f;
#pragma unroll
    for (int jj = 0; jj < 8; ++jj) { v[jj] = fmaxf(v[jj], 0.0f); lmax = fmaxf(lmax, v[jj]); }
#pragma unroll
    for (int off = 32; off > 0; off >>= 1)
        lmax = fmaxf(lmax, __shfl_down(lmax, off, 64));
    if ((tid & 63) == 0) wred[tid >> 6] = lmax;
    __syncthreads();
    if (tid == 0) bcast = fmaxf(fmaxf(wred[0], wred[1]), fmaxf(wred[2], wred[3]));
    __syncthreads();
    const float rmax = bcast;

    float lsum = 0.0f;
    if (active) {
#pragma unroll
        for (int jj = 0; jj < 8; ++jj) { v[jj] = __expf(v[jj] - rmax); lsum += v[jj]; }
    }
#pragma unroll
    for (int off = 32; off > 0; off >>= 1)
        lsum += __shfl_down(lsum, off, 64);
    if ((tid & 63) == 0) wred[tid >> 6] = lsum;
    __syncthreads();
    if (tid == 0) bcast = wred[0] + wred[1] + wred[2] + wred[3];
    __syncthreads();
    const float inv = 1.0f / bcast;

    if (tid < 252) {   // threads 250,251 write the k 2000..2015 zero pad
        bf16x8 pk;
#pragma unroll
        for (int jj = 0; jj < 8; ++jj)
            pk[jj] = (bf16)(active ? v[jj] * inv : 0.0f);
        const int kb = j0 >> 5, q = (j0 >> 3) & 3;
        const int nt = row >> 6, r = row & 63;
        *(bf16x8*)&Sp[((size_t)(kb * 32 + nt) * 256 + q * 64 + r) * 8] = pk;
    }
}

// ---------------------------------------------------------------------------
// Kernel 2: x [b][m][c] fp32 -> xTp packed tiles [b][kb][q][c][j] bf16
//           + xbf row-major [b][m][c] bf16.   (b-slab stride = KB3 slabs)
// ---------------------------------------------------------------------------
__global__ __launch_bounds__(256) void transpose_pack_x(
    const float* __restrict__ X, bf16* __restrict__ Xtp, bf16* __restrict__ Xbf)
{
    const int b  = blockIdx.y;
    const int m0 = blockIdx.x * 64;
    const int tid = threadIdx.x;
    __shared__ bf16 T[64][72];
#pragma unroll
    for (int i = 0; i < 4; ++i) {
        int idx = i * 256 + tid;
        int r  = idx >> 4;
        int c4 = (idx & 15) * 4;
        int m  = m0 + r;
        float4 v = make_float4(0.f, 0.f, 0.f, 0.f);
        if (m < N_NODES)
            v = *(const float4*)&X[((size_t)b * N_NODES + m) * DIM + c4];
        bf16x4pk pk;
        pk.v[0] = (bf16)v.x; pk.v[1] = (bf16)v.y;
        pk.v[2] = (bf16)v.z; pk.v[3] = (bf16)v.w;
        if (m < N_NODES)
            *(bf16x4pk*)&Xbf[((size_t)b * N_NODES + m) * DIM + c4] = pk;
        T[c4 + 0][r] = pk.v[0];
        T[c4 + 1][r] = pk.v[1];
        T[c4 + 2][r] = pk.v[2];
        T[c4 + 3][r] = pk.v[3];
    }
    __syncthreads();
#pragma unroll
    for (int i = 0; i < 2; ++i) {
        int idx = i * 256 + tid;       // 0..511
        int c   = idx >> 3;
        int mch = idx & 7;             // 8-elem m-chunk within the 64-m block
        int kb  = (m0 >> 5) + (mch >> 2);
        if (kb < KB) {
            int q = mch & 3;
            bf16x8 vv = *(const bf16x8*)&T[c][mch * 8];
            *(bf16x8*)&Xtp[((size_t)(b * KB3 + kb) * 256 + q * 64 + c) * 8] = vv;
        }
    }
}

// ---------------------------------------------------------------------------
// Kernel 3: spmm, double-buffered LDS with 3-kb stages (22 barriers, not 64).
// Block = 128n x 64c (one batch), 4 waves (each 32n x 64c). Per stage:
// barrier(drain) -> ds_read 3 kb of frags -> issue next 3-kb DMA -> 24 MFMAs.
// One drain amortized over 3 k-blocks; 2 blocks/CU overlap drains.
// LDS: 2 x (24 KB A + 12 KB B) = 72 KB.
// ---------------------------------------------------------------------------
__global__ __launch_bounds__(256, 2) void spmm_pack(
    const bf16* __restrict__ Ap, const bf16* __restrict__ Btp,
    bf16* __restrict__ Ybf, bf16* __restrict__ Ytp, int write_ytp)
{
    const int ntB = blockIdx.x;          // 0..15 (fastest -> XCD = ntB % 8)
    const int b   = blockIdx.y;
    const int n0  = ntB * 128;
    const int tid = threadIdx.x;
    const int lane = tid & 63, wave = tid >> 6;
    const int l15 = lane & 15, quad = lane >> 4;

    __shared__ bf16 As[2][3 * 4096];   // 24 KB per buffer (128 rows x 3x32 k)
    __shared__ bf16 Bs[2][3 * 2048];   // 12 KB per buffer ( 64 cols x 3x32 k)

    const bf16* aslab = Ap  + (size_t)(ntB * 2) * 2048 + tid * 8;  // + kb*32*2048
    const bf16* bslab = Btp + (size_t)(b * KB3) * 2048 + tid * 8;  // + kb*2048

#define DMA_STAGE(buf, kb0_) {                                        \
        _Pragma("unroll")                                             \
        for (int j = 0; j < 3; ++j) {                                 \
            const bf16* pa = aslab + (size_t)(kb0_ + j) * (32 * 2048);\
            const bf16* pb = bslab + (size_t)(kb0_ + j) * 2048;       \
            gl_lds16(pa,        &As[buf][j * 4096 + tid * 8]);        \
            gl_lds16(pa + 2048, &As[buf][j * 4096 + 2048 + tid * 8]); \
            gl_lds16(pb,        &Bs[buf][j * 2048 + tid * 8]);  } }

    f32x4 acc[2][4] = {};
    const int ga = (wave >> 1) * 256 + quad * 64 + (wave & 1) * 32; // A granule base
    const int gb = quad * 64;                                       // B granule base

    DMA_STAGE(0, 0);
#pragma unroll 1
    for (int s = 0; s < 22; ++s) {
        const int cur = s & 1;
        __syncthreads();               // drains vmcnt(0): buf[cur] ready
        bf16x8 af[3][2], bfr[3][4];
#pragma unroll
        for (int j = 0; j < 3; ++j) {
#pragma unroll
            for (int t = 0; t < 2; ++t)
                af[j][t]  = *(const bf16x8*)&As[cur][j * 4096 + (ga + t * 16 + l15) * 8];
#pragma unroll
            for (int t = 0; t < 4; ++t)
                bfr[j][t] = *(const bf16x8*)&Bs[cur][j * 2048 + (gb + t * 16 + l15) * 8];
        }
        if (s + 1 < 22) DMA_STAGE(cur ^ 1, (s + 1) * 3);
#pragma unroll
        for (int j = 0; j < 3; ++j)
#pragma unroll
            for (int rt = 0; rt < 2; ++rt)
#pragma unroll
                for (int ct = 0; ct < 4; ++ct)
                    acc[rt][ct] = __builtin_amdgcn_mfma_f32_16x16x32_bf16(
                        af[j][rt], bfr[j][ct], acc[rt][ct], 0, 0, 0);
    }
#undef DMA_STAGE

    // Epilogue. C/D layout: col = lane&15, row = quad*4 + reg
#pragma unroll
    for (int rt = 0; rt < 2; ++rt) {
        const int nbase = n0 + wave * 32 + rt * 16 + quad * 4;
#pragma unroll
        for (int ct = 0; ct < 4; ++ct) {
            const int c = ct * 16 + l15;
#pragma unroll
            for (int r = 0; r < 4; ++r) {
                int n = nbase + r;
                if (n < N_NODES)
                    Ybf[((size_t)b * N_NODES + n) * DIM + c] = (bf16)acc[rt][ct][r];
            }
            if (write_ytp && nbase + 4 <= N_NODES) {
                const int kb2 = nbase >> 5;
                const int kq  = (nbase & 31) >> 3;
                const int j4  = nbase & 7;       // 0 or 4
                bf16x4pk pk;
                pk.v[0] = (bf16)acc[rt][ct][0];
                pk.v[1] = (bf16)acc[rt][ct][1];
                pk.v[2] = (bf16)acc[rt][ct][2];
                pk.v[3] = (bf16)acc[rt][ct][3];
                *(bf16x4pk*)&Ytp[((size_t)(b * KB3 + kb2) * 256 + kq * 64 + c) * 8 + j4] = pk;
            }
        }
    }
}

// ---------------------------------------------------------------------------
// Kernel 4a: wpT2[col][d] (d pad 32) + embp[n][d] (d pad 32), bf16;
// also zero-fills Sp slabs 63..65 (A=0 makes the 66-slab loop exact;
// B-slab garbage there is finite 0xAA-pattern bf16, 0*B == 0).
// ---------------------------------------------------------------------------
#define Z0   (WCOLS * 32)
#define Z1   (Z0 + N_NODES * 32)
#define Z2   (Z1 + 3 * NP * 32)
__global__ __launch_bounds__(256) void prep_small(
    const float* __restrict__ wp, const float* __restrict__ emb,
    bf16* __restrict__ wpT2, bf16* __restrict__ embp, bf16* __restrict__ Sp63)
{
    int idx = blockIdx.x * 256 + threadIdx.x;
    if (idx < Z0) {
        int col = idx >> 5, d = idx & 31;
        int o  = col / KI;
        int kk = col - o * KI;
        int cheb = kk >> 6, i = kk & 63;
        float v = (d < EMB) ? wp[(((d * 3 + cheb) * 64 + i) * 64) + o] : 0.0f;
        wpT2[idx] = (bf16)v;
    } else if (idx < Z1) {
        int j = idx - Z0;
        int n = j >> 5, d = j & 31;
        float v = (d < EMB) ? emb[n * EMB + d] : 0.0f;
        embp[j] = (bf16)v;
    } else if (idx < Z2) {
        Sp63[idx - Z1] = (bf16)0.0f;
    }
}

// ---------------------------------------------------------------------------
// Kernel 4b: W[n][col] = sum_d embp[n][d] * wpT2[col][d]  (bf16 out)
// ---------------------------------------------------------------------------
__global__ __launch_bounds__(256) void prep_W_mfma(
    const bf16* __restrict__ embp, const bf16* __restrict__ wpT2,
    bf16* __restrict__ W)
{
    const int colbase = blockIdx.x * 256;
    const int n0      = blockIdx.y * 16;
    const int tid  = threadIdx.x;
    const int lane = tid & 63, wave = tid >> 6;
    const int l15 = lane & 15, quad = lane >> 4;

    __shared__ bf16 Cs[16][264];

    const bf16x8 af = *(const bf16x8*)&embp[(n0 + l15) * 32 + quad * 8];
    const f32x4 zero = {};
#pragma unroll
    for (int ct = 0; ct < 4; ++ct) {
        const int col = colbase + wave * 64 + ct * 16 + l15;
        bf16x8 bfr = *(const bf16x8*)&wpT2[(size_t)col * 32 + quad * 8];
        f32x4 acc = __builtin_amdgcn_mfma_f32_16x16x32_bf16(af, bfr, zero, 0, 0, 0);
#pragma unroll
        for (int r = 0; r < 4; ++r)
            Cs[quad * 4 + r][wave * 64 + ct * 16 + l15] = (bf16)acc[r];
    }
    __syncthreads();
    {
        const int row = tid >> 4;
        const int c16 = (tid & 15) * 16;
        bf16x8 v0 = *(const bf16x8*)&Cs[row][c16];
        bf16x8 v1 = *(const bf16x8*)&Cs[row][c16 + 8];
        bf16* dst = &W[(size_t)(n0 + row) * WCOLS + colbase + c16];
        *(bf16x8*)dst       = v0;
        *(bf16x8*)(dst + 8) = v1;
    }
}

// ---------------------------------------------------------------------------
// Kernel 5: per-node combine (bf16 inputs).
// ---------------------------------------------------------------------------
__global__ __launch_bounds__(256) void combine_node(
    const bf16* __restrict__ xbf, const bf16* __restrict__ y1bf,
    const bf16* __restrict__ y2bf, const float* __restrict__ emb,
    const float* __restrict__ bp, const bf16* __restrict__ W,
    float* __restrict__ out)
{
    const int n   = blockIdx.x;
    const int tid = threadIdx.x;
    const int lane = tid & 63, wave = tid >> 6;
    const int l15 = lane & 15, quad = lane >> 4;

    __shared__ bf16 As[BATCH][200];
    __shared__ bf16 Ws[DIM][200];
    __shared__ float bias_s[DIM];
    __shared__ float emb_s[EMB];

    if (tid < EMB) emb_s[tid] = emb[n * EMB + tid];

    {
        const int b  = tid >> 3;
        const int c8 = (tid & 7) * 8;
        const size_t base = ((size_t)b * N_NODES + n) * DIM + c8;
        bf16x8 vx = *(const bf16x8*)&xbf [base];
        bf16x8 v1 = *(const bf16x8*)&y1bf[base];
        bf16x8 v2 = *(const bf16x8*)&y2bf[base];
        bf16x8 p2;
#pragma unroll
        for (int e = 0; e < 8; ++e)
            p2[e] = (bf16)(2.0f * (float)v2[e] - (float)vx[e]);
        *(bf16x8*)&As[b][c8]       = vx;
        *(bf16x8*)&As[b][64 + c8]  = v1;
        *(bf16x8*)&As[b][128 + c8] = p2;
    }
    {
        const bf16* Wn = W + (size_t)n * WCOLS;
#pragma unroll
        for (int jj = 0; jj < 6; ++jj) {
            int chunk = jj * 256 + tid;
            int o  = chunk / 24;
            int kc = chunk - o * 24;
            bf16x8 v = *(const bf16x8*)&Wn[(size_t)chunk * 8];
            *(bf16x8*)&Ws[o][kc * 8] = v;
        }
    }
    __syncthreads();

    if (tid < DIM) {
        float s = 0.0f;
#pragma unroll
        for (int d = 0; d < EMB; ++d) s += emb_s[d] * bp[d * DIM + tid];
        bias_s[tid] = s;
    }

    bf16x8 af[2][6];
#pragma unroll
    for (int mt = 0; mt < 2; ++mt)
#pragma unroll
        for (int ks = 0; ks < 6; ++ks)
            af[mt][ks] = *(const bf16x8*)&As[mt * 16 + l15][ks * 32 + quad * 8];

    f32x4 acc[2] = {};
#pragma unroll
    for (int ks = 0; ks < 6; ++ks) {
        bf16x8 bfr = *(const bf16x8*)&Ws[wave * 16 + l15][ks * 32 + quad * 8];
        acc[0] = __builtin_amdgcn_mfma_f32_16x16x32_bf16(af[0][ks], bfr, acc[0], 0, 0, 0);
        acc[1] = __builtin_amdgcn_mfma_f32_16x16x32_bf16(af[1][ks], bfr, acc[1], 0, 0, 0);
    }
    __syncthreads();

    const int o = wave * 16 + l15;
    const float bv = bias_s[o];
#pragma unroll
    for (int mt = 0; mt < 2; ++mt)
#pragma unroll
        for (int r = 0; r < 4; ++r) {
            int b = mt * 16 + quad * 4 + r;
            out[((size_t)b * N_NODES + n) * DIM + o] = acc[mt][r] + bv;
        }
}

// ---------------------------------------------------------------------------
extern "C" void kernel_launch(void* const* d_in, const int* in_sizes, int n_in,
                              void* d_out, int out_size, void* d_ws, size_t ws_size,
                              hipStream_t stream) {
    const float* x   = (const float*)d_in[0];  // [32,2000,64]
    const float* emb = (const float*)d_in[1];  // [2000,16]
    const float* nv1 = (const float*)d_in[2];  // [2000,16]
    const float* nv2 = (const float*)d_in[3];  // [16,2000]
    const float* wp  = (const float*)d_in[4];  // [16,3,64,64]
    const float* bp  = (const float*)d_in[5];  // [16,64]
    float* out = (float*)d_out;                // [32,2000,64]

    char* w = (char*)d_ws;
    bf16* Sp   = (bf16*)w;  w += (size_t)KB3 * NP * 32 * 2;           //  8.65 MB
    bf16* xTp  = (bf16*)w;  w += (size_t)BATCH * KB3 * DIM * 32 * 2;  //  8.65 MB
    bf16* y1Tp = (bf16*)w;  w += (size_t)BATCH * KB3 * DIM * 32 * 2;  //  8.65 MB
    bf16* xbf  = (bf16*)w;  w += (size_t)BATCH * N_NODES * DIM * 2;   //  8.19 MB
    bf16* y1bf = (bf16*)w;  w += (size_t)BATCH * N_NODES * DIM * 2;   //  8.19 MB
    bf16* y2bf = (bf16*)w;  w += (size_t)BATCH * N_NODES * DIM * 2;   //  8.19 MB
    bf16* wpT2 = (bf16*)w;  w += (size_t)WCOLS * 32 * 2;              //  0.79 MB
    bf16* embp = (bf16*)w;  w += (size_t)N_NODES * 32 * 2;            //  0.13 MB
    bf16* W    = (bf16*)w;                                            // 49.15 MB

    adj_softmax_pack<<<N_NODES, 256, 0, stream>>>(nv1, nv2, Sp);
    transpose_pack_x<<<dim3(32, BATCH), 256, 0, stream>>>(x, xTp, xbf);
    prep_small<<<(Z2 + 255) / 256, 256, 0, stream>>>(
        wp, emb, wpT2, embp, Sp + (size_t)63 * NP * 32);
    prep_W_mfma<<<dim3(WCOLS / 256, N_NODES / 16), 256, 0, stream>>>(embp, wpT2, W);
    spmm_pack<<<dim3(16, BATCH), 256, 0, stream>>>(Sp, xTp,  y1bf, y1Tp, 1);
    spmm_pack<<<dim3(16, BATCH), 256, 0, stream>>>(Sp, y1Tp, y2bf, y1Tp, 0);
    combine_node<<<N_NODES, 256, 0, stream>>>(xbf, y1bf, y2bf, emb, bp, W, out);
}